// Round 12
// baseline (220.223 us; speedup 1.0000x reference)
//
#include <hip/hip_runtime.h>
#include <math.h>

#define B_ROWS 2048
#define P_ROWS 100000
#define D_DIM  128
#define NPC    64                 // pool chunks (grid.x of gemm)
#define NT     782                // ceil(100000/128) pool tiles
#define TILEB  32768              // 128 pool-rows x 128 bf16 (256 B/row)
#define NCAND  (NPC * 3)          // 192 screened candidates per row

typedef short short8 __attribute__((ext_vector_type(8)));
typedef float f32x4  __attribute__((ext_vector_type(4)));
typedef unsigned long long u64;

// bf16 RNE
__device__ __forceinline__ unsigned short f2bf(float f) {
    unsigned u = __float_as_uint(f);
    u += 0x7fffu + ((u >> 16) & 1u);
    return (unsigned short)(u >> 16);
}

__device__ __forceinline__ void async16(const char* g, char* l) {
    __builtin_amdgcn_global_load_lds(
        (const __attribute__((address_space(1))) unsigned int*)g,
        (__attribute__((address_space(3))) unsigned int*)l,
        16, 0, 0);
}

// u64 branchless top-3 insert
__device__ __forceinline__ void kins64(u64 k, u64& t0, u64& t1, u64& t2) {
    u64 m0 = (t0 < k) ? t0 : k;  t0 = (t0 < k) ? k : t0;
    u64 m1 = (t1 < m0) ? t1 : m0; t1 = (t1 < m0) ? m0 : t1;
    t2 = (t2 < m1) ? m1 : t2;
}

// fp64 top-3 insert with index tie-break (lower index wins)
__device__ __forceinline__ void ins3d(double v, int c,
                                      double& v0, int& i0,
                                      double& v1, int& i1,
                                      double& v2, int& i2) {
    bool b0 = (v > v0) || (v == v0 && c < i0);
    bool b1 = (v > v1) || (v == v1 && c < i1);
    bool b2 = (v > v2) || (v == v2 && c < i2);
    if (b0)      { v2 = v1; i2 = i1; v1 = v0; i1 = i0; v0 = v; i0 = c; }
    else if (b1) { v2 = v1; i2 = i1; v1 = v;  i1 = c; }
    else if (b2) { v2 = v;  i2 = c; }
}

// ---------------------------------------------------------------------------
// Kernel 1: pack sess -> hi-bf16, linear 256 B/row. One wave per row.
// ---------------------------------------------------------------------------
__global__ void pack_sess_kernel(const float* __restrict__ sess,
                                 char* __restrict__ sess2) {
    int row  = blockIdx.x * 4 + (threadIdx.x >> 6);
    int lane = threadIdx.x & 63;
    float2 v = ((const float2*)(sess + (size_t)row * D_DIM))[lane];
    float s = v.x * v.x + v.y * v.y;
    #pragma unroll
    for (int o = 32; o > 0; o >>= 1) s += __shfl_xor(s, o);
    float inv = 1.0f / sqrtf(s + (float)D_DIM * 1e-6f);
    ushort2 hv;
    hv.x = f2bf(v.x * inv);
    hv.y = f2bf(v.y * inv);
    *(ushort2*)(sess2 + (size_t)row * 256 + lane * 4) = hv;
}

// ---------------------------------------------------------------------------
// Kernel 2: pack pool -> pool2[T][c][slot][16B] hi-bf16, XOR-swizzled.
// RESTRUCTURED (R12): two-pass (no regs held across barriers; phase-2 reload
// hits L1/L2) and NO atomics — per-block dim-sums to S_part[T][128], reduced
// by reduce_S_kernel. R11's version held 64 VGPRs of float4 across the first
// barrier and fired 100k atomicAdds onto 128 addresses (~83 us hidden cost).
// ---------------------------------------------------------------------------
__global__ void pack_pool_kernel(const float* __restrict__ pool,
                                 char* __restrict__ pool2,
                                 float* __restrict__ S_part) {
    __shared__ float red[128][17];
    __shared__ float s_inv[128];
    __shared__ float red2[16][128];
    const int tid = threadIdx.x;
    const int T   = blockIdx.x;
    const int c0  = tid >> 4;
    const int g   = tid & 15;

    // phase 1: per-row sum of squares into LDS
    #pragma unroll
    for (int it = 0; it < 8; ++it) {
        int c = it * 16 + c0;
        int n = T * 128 + c;
        float4 a = make_float4(0.f, 0.f, 0.f, 0.f), b = a;
        if (n < P_ROWS) {
            const float4* src = (const float4*)(pool + (size_t)n * D_DIM + g * 8);
            a = src[0]; b = src[1];
        }
        red[c][g] = a.x*a.x + a.y*a.y + a.z*a.z + a.w*a.w
                  + b.x*b.x + b.y*b.y + b.z*b.z + b.w*b.w;
    }
    __syncthreads();
    if (tid < 128) {
        float s = 0.f;
        #pragma unroll
        for (int j = 0; j < 16; ++j) s += red[tid][j];
        s_inv[tid] = 1.0f / sqrtf(s + (float)D_DIM * 1e-6f);
    }
    __syncthreads();

    // phase 2: reload (L1/L2-hot), scale, convert, store; accumulate dim-sums
    float sacc[8] = {0.f,0.f,0.f,0.f,0.f,0.f,0.f,0.f};
    #pragma unroll
    for (int it = 0; it < 8; ++it) {
        int c = it * 16 + c0;
        int n = T * 128 + c;
        float4 a = make_float4(0.f, 0.f, 0.f, 0.f), b = a;
        if (n < P_ROWS) {
            const float4* src = (const float4*)(pool + (size_t)n * D_DIM + g * 8);
            a = src[0]; b = src[1];
        }
        float inv = s_inv[c];
        const float f[8] = {a.x, a.y, a.z, a.w, b.x, b.y, b.z, b.w};
        short8 hv;
        #pragma unroll
        for (int j = 0; j < 8; ++j) {
            float w = f[j] * inv;
            hv[j] = (short)f2bf(w);
            sacc[j] += w;
        }
        *(short8*)(pool2 + (size_t)T * TILEB + c * 256 + ((g ^ (c & 7)) * 16)) = hv;
    }
    #pragma unroll
    for (int j = 0; j < 8; ++j) red2[c0][g * 8 + j] = sacc[j];
    __syncthreads();
    if (tid < 128) {
        float s = 0.f;
        #pragma unroll
        for (int k = 0; k < 16; ++k) s += red2[k][tid];
        S_part[(size_t)T * 128 + tid] = s;
    }
}

// ---------------------------------------------------------------------------
// Kernel 2b: reduce S_part[NT][128] -> S[128]. One block, 256 threads
// (two halves of the T-range), unrolled 8-deep to pipeline the loads.
// ---------------------------------------------------------------------------
__global__ void reduce_S_kernel(const float* __restrict__ S_part,
                                float* __restrict__ S) {
    __shared__ float part[256];
    const int d = threadIdx.x & 127;
    const int h = threadIdx.x >> 7;
    const int t0 = h * (NT / 2);
    const int t1 = (h == 0) ? (NT / 2) : NT;
    float s = 0.f;
    #pragma unroll 8
    for (int T = t0; T < t1; ++T) s += S_part[(size_t)T * 128 + d];
    part[threadIdx.x] = s;
    __syncthreads();
    if (threadIdx.x < 128) S[threadIdx.x] = part[threadIdx.x] + part[threadIdx.x + 128];
}

// ---------------------------------------------------------------------------
// Kernel 3: hi-bf16 MFMA cosine SCREEN, top-3 keys only (no z).
// Identical to R11 (93.4 us, occupancy 30%, VGPR 52, no spill).
// NOTE: launch_bounds stays (256,2) — (256,4) forces a 128-reg budget and
// spills catastrophically (R8: ~850 MB scratch, 2.7x regression).
// ---------------------------------------------------------------------------
__launch_bounds__(256, 2)
__global__ void gemm_topk_kernel(const char* __restrict__ sess2,
                                 const char* __restrict__ pool2,
                                 u64* __restrict__ partials) {
    __shared__ char lds[TILEB];

    const int tid = threadIdx.x;
    const int w   = tid >> 6;
    const int L   = tid & 63;
    const int q   = L >> 4;
    const int l15 = L & 15;
    const int l7  = L & 7;
    const int pc  = blockIdx.x;
    const int mt  = blockIdx.y;
    const int rowbase = mt * 128 + w * 32;

    short8 afrag[2][4];
    #pragma unroll
    for (int i = 0; i < 2; ++i)
        #pragma unroll
        for (int ks = 0; ks < 4; ++ks)
            afrag[i][ks] = *(const short8*)(sess2 +
                (size_t)(rowbase + i * 16 + l15) * 256 + (ks * 4 + q) * 16);

    int soks[4];
    #pragma unroll
    for (int ks = 0; ks < 4; ++ks) soks[ks] = ((ks * 4 + q) ^ l7) * 16;
    const char* lbase = lds + l15 * 256;

    float key0[2][4], key1[2][4], key2[2][4];
    #pragma unroll
    for (int i = 0; i < 2; ++i)
        #pragma unroll
        for (int r = 0; r < 4; ++r)
            key0[i][r] = key1[i][r] = key2[i][r] = -1e30f;

    int tloc = 0;
    for (int T = pc; T < NT; T += NPC, ++tloc) {
        __syncthreads();
        const char* tb = pool2 + (size_t)T * TILEB;
        #pragma unroll
        for (int rr = 0; rr < 8; ++rr) {
            int idx = rr * 256 + tid;
            async16(tb + idx * 16, lds + idx * 16);
        }
        __syncthreads();

        #pragma unroll
        for (int qt = 0; qt < 4; ++qt) {
            f32x4 acc[2][2];
            #pragma unroll
            for (int i = 0; i < 2; ++i) {
                acc[i][0] = (f32x4){0.f,0.f,0.f,0.f};
                acc[i][1] = (f32x4){0.f,0.f,0.f,0.f};
            }
            #pragma unroll
            for (int ks = 0; ks < 4; ++ks) {
                const char* cb = lbase + qt * 8192 + soks[ks];
                short8 b0 = *(const short8*)(cb);
                short8 b1 = *(const short8*)(cb + 16 * 256);
                #pragma unroll
                for (int i = 0; i < 2; ++i) {
                    acc[i][0] = __builtin_amdgcn_mfma_f32_16x16x32_bf16(
                        afrag[i][ks], b0, acc[i][0], 0, 0, 0);
                    acc[i][1] = __builtin_amdgcn_mfma_f32_16x16x32_bf16(
                        afrag[i][ks], b1, acc[i][1], 0, 0, 0);
                }
            }
            #pragma unroll
            for (int j = 0; j < 2; ++j) {
                const unsigned pos = (unsigned)(tloc * 8 + qt * 2 + j);
                #pragma unroll
                for (int i = 0; i < 2; ++i)
                    #pragma unroll
                    for (int r = 0; r < 4; ++r) {
                        float v = acc[i][j][r];
                        float kf = __uint_as_float(
                            (__float_as_uint(v) & 0xFFFFFF80u) | pos);
                        float o0 = key0[i][r], o1 = key1[i][r];
                        key0[i][r] = fmaxf(o0, kf);
                        key1[i][r] = __builtin_amdgcn_fmed3f(kf, o0, key1[i][r]);
                        key2[i][r] = __builtin_amdgcn_fmed3f(kf, o1, key2[i][r]);
                    }
            }
        }
    }

    #pragma unroll
    for (int i = 0; i < 2; ++i)
        #pragma unroll
        for (int r = 0; r < 4; ++r) {
            float kk[3] = {key0[i][r], key1[i][r], key2[i][r]};
            u64 t0 = 0ull, t1 = 0ull, t2 = 0ull;
            #pragma unroll
            for (int k = 0; k < 3; ++k) {
                unsigned u   = __float_as_uint(kk[k]);
                unsigned pos = u & 127u;
                unsigned vb  = u & 0xFFFFFF80u;
                unsigned mono = (vb & 0x80000000u) ? ~vb : (vb | 0x80000000u);
                unsigned col = (unsigned)((pc + (int)(pos >> 3) * NPC) * 128
                                          + (int)(pos & 7u) * 16 + l15);
                u64 key = ((u64)mono << 32) | (u64)(131071u - col);
                kins64(key, t0, t1, t2);
            }
            #pragma unroll
            for (int m = 1; m < 16; m <<= 1) {
                u64 r0 = __shfl_xor(t0, m);
                u64 r1 = __shfl_xor(t1, m);
                u64 r2 = __shfl_xor(t2, m);
                kins64(r0, t0, t1, t2);
                kins64(r1, t0, t1, t2);
                kins64(r2, t0, t1, t2);
            }
            if (l15 == 0) {
                int row = rowbase + i * 16 + q * 4 + r;
                u64* o = partials + ((size_t)row * NPC + pc) * 3;
                o[0] = t0; o[1] = t1; o[2] = t2;
            }
        }
}

// ---------------------------------------------------------------------------
// Kernel 4: per row (one wave) — merge 192 exact-screen u64 keys -> top-8,
// fp64 rescore ONLY those 8, exact top-3 (index tie-break), moment-z,
// double softmax, gather, write. Identical to R11.
// ---------------------------------------------------------------------------
__launch_bounds__(256)
__global__ void finalize_kernel(const float* __restrict__ sess,
                                const float* __restrict__ pool,
                                const u64* __restrict__ partials,
                                const float* __restrict__ S,
                                float* __restrict__ out_neighbor,
                                float* __restrict__ out_costopk,
                                float* __restrict__ out_sesstopk) {
    const int row = blockIdx.x * 4 + (threadIdx.x >> 6);
    const int L   = threadIdx.x & 63;

    const u64* pk = partials + (size_t)row * NCAND + 3 * L;
    u64 t0 = pk[0], t1 = pk[1], t2 = pk[2];

    u64 cand[8];
    #pragma unroll
    for (int k = 0; k < 8; ++k) {
        u64 m = t0;
        #pragma unroll
        for (int o = 1; o < 64; o <<= 1) {
            u64 r = __shfl_xor(m, o);
            m = (r > m) ? r : m;
        }
        cand[k] = m;
        bool pop = (t0 == m);
        t0 = pop ? t1 : t0;
        t1 = pop ? t2 : t1;
        t2 = pop ? 0ull : t2;
    }

    const float2 sa = ((const float2*)(sess + (size_t)row * D_DIM))[L];
    int    idx[8];
    float2 pb[8];
    #pragma unroll
    for (int j = 0; j < 8; ++j) {
        idx[j] = 131071 - (int)(cand[j] & 0x1FFFFull);
        bool ok = idx[j] < P_ROWS;
        pb[j] = ok ? ((const float2*)(pool + (size_t)idx[j] * D_DIM))[L]
                   : make_float2(0.f, 0.f);
    }

    double na  = (double)sa.x * sa.x + (double)sa.y * sa.y;
    double dss = (double)sa.x * S[2 * L] + (double)sa.y * S[2 * L + 1];
    #pragma unroll
    for (int o = 32; o > 0; o >>= 1) {
        na  += __shfl_xor(na, o);
        dss += __shfl_xor(dss, o);
    }
    na += (double)D_DIM * 1e-6;

    double v[8];
    #pragma unroll
    for (int j = 0; j < 8; ++j) {
        double dot = (double)sa.x * pb[j].x + (double)sa.y * pb[j].y;
        double nb  = (double)pb[j].x * pb[j].x + (double)pb[j].y * pb[j].y;
        #pragma unroll
        for (int o = 32; o > 0; o >>= 1) {
            dot += __shfl_xor(dot, o);
            nb  += __shfl_xor(nb, o);
        }
        v[j] = (idx[j] < P_ROWS)
             ? dot / sqrt(na * (nb + (double)D_DIM * 1e-6))
             : -1e300;
    }

    double v0 = -1e300, v1 = -1e300, v2 = -1e300;
    int    i0 = 0x7fffffff, i1 = 0x7fffffff, i2 = 0x7fffffff;
    #pragma unroll
    for (int j = 0; j < 8; ++j) ins3d(v[j], idx[j], v0, i0, v1, i1, v2, i2);

    double z  = (double)P_ROWS + dss / sqrt(na) + 390.625;
    double c0 = exp(v0) / z, c1 = exp(v1) / z, c2 = exp(v2) / z;
    double e1 = exp(c1 - c0), e2 = exp(c2 - c0);
    double inv = 1.0 / (1.0 + e1 + e2);
    float  w0 = (float)inv, w1 = (float)(e1 * inv), w2 = (float)(e2 * inv);

    float2 g0 = ((const float2*)(pool + (size_t)i0 * D_DIM))[L];
    float2 g1 = ((const float2*)(pool + (size_t)i1 * D_DIM))[L];
    float2 g2 = ((const float2*)(pool + (size_t)i2 * D_DIM))[L];
    ((float2*)(out_sesstopk + ((size_t)row * 3 + 0) * D_DIM))[L] = g0;
    ((float2*)(out_sesstopk + ((size_t)row * 3 + 1) * D_DIM))[L] = g1;
    ((float2*)(out_sesstopk + ((size_t)row * 3 + 2) * D_DIM))[L] = g2;
    float2 nbv;
    nbv.x = w0 * g0.x + w1 * g1.x + w2 * g2.x;
    nbv.y = w0 * g0.y + w1 * g1.y + w2 * g2.y;
    ((float2*)(out_neighbor + (size_t)row * D_DIM))[L] = nbv;
    if (L == 0) {
        out_costopk[row * 3 + 0] = w0;
        out_costopk[row * 3 + 1] = w1;
        out_costopk[row * 3 + 2] = w2;
    }
}

// ---------------------------------------------------------------------------
extern "C" void kernel_launch(void* const* d_in, const int* in_sizes, int n_in,
                              void* d_out, int out_size, void* d_ws, size_t ws_size,
                              hipStream_t stream) {
    const float* sess = (const float*)d_in[0];   // [2048,128]
    const float* pool = (const float*)d_in[1];   // [100000,128]
    float* out = (float*)d_out;
    float* out_neighbor = out;
    float* out_costopk  = out + (size_t)B_ROWS * D_DIM;
    float* out_sesstopk = out_costopk + (size_t)B_ROWS * 3;

    // ws: S(512B) | S_part(400KB) | partials(3.1MB) | sess2(512KB) | pool2(25.6MB)
    float* Svec     = (float*)d_ws;
    float* S_part   = (float*)((char*)d_ws + 512);
    u64*   partials = (u64*)((char*)d_ws + 512 + (size_t)NT * 128 * 4);
    char*  sess2    = (char*)partials + (size_t)B_ROWS * NCAND * 8;
    char*  pool2    = sess2 + (size_t)B_ROWS * 256;

    pack_sess_kernel<<<B_ROWS / 4, 256, 0, stream>>>(sess, sess2);
    pack_pool_kernel<<<NT, 256, 0, stream>>>(pool, pool2, S_part);
    reduce_S_kernel<<<1, 256, 0, stream>>>(S_part, Svec);

    dim3 g3(NPC, B_ROWS / 128);
    gemm_topk_kernel<<<g3, 256, 0, stream>>>(sess2, pool2, partials);

    finalize_kernel<<<B_ROWS / 4, 256, 0, stream>>>(
        sess, pool, partials, Svec, out_neighbor, out_costopk, out_sesstopk);
}

// Round 13
// 213.592 us; speedup vs baseline: 1.0310x; 1.0310x over previous
//
#include <hip/hip_runtime.h>
#include <math.h>

#define B_ROWS 2048
#define P_ROWS 100000
#define D_DIM  128
#define NPC    128                // pool chunks (grid.x of gemm)
#define NTP    782                // pack_pool grid (128 rows per block)
#define NT64   1563               // 64-row pool tiles (gemm T-loop)
#define TILEB  16384              // 64 pool-rows x 128 bf16 (256 B/row)
#define NCAND  (NPC * 3)          // 384 screened candidates per row

typedef short short8 __attribute__((ext_vector_type(8)));
typedef float f32x4  __attribute__((ext_vector_type(4)));
typedef unsigned long long u64;

// bf16 RNE
__device__ __forceinline__ unsigned short f2bf(float f) {
    unsigned u = __float_as_uint(f);
    u += 0x7fffu + ((u >> 16) & 1u);
    return (unsigned short)(u >> 16);
}

__device__ __forceinline__ void async16(const char* g, char* l) {
    __builtin_amdgcn_global_load_lds(
        (const __attribute__((address_space(1))) unsigned int*)g,
        (__attribute__((address_space(3))) unsigned int*)l,
        16, 0, 0);
}

// u64 branchless top-3 insert
__device__ __forceinline__ void kins64(u64 k, u64& t0, u64& t1, u64& t2) {
    u64 m0 = (t0 < k) ? t0 : k;  t0 = (t0 < k) ? k : t0;
    u64 m1 = (t1 < m0) ? t1 : m0; t1 = (t1 < m0) ? m0 : t1;
    t2 = (t2 < m1) ? m1 : t2;
}

// fp64 top-3 insert with index tie-break (lower index wins)
__device__ __forceinline__ void ins3d(double v, int c,
                                      double& v0, int& i0,
                                      double& v1, int& i1,
                                      double& v2, int& i2) {
    bool b0 = (v > v0) || (v == v0 && c < i0);
    bool b1 = (v > v1) || (v == v1 && c < i1);
    bool b2 = (v > v2) || (v == v2 && c < i2);
    if (b0)      { v2 = v1; i2 = i1; v1 = v0; i1 = i0; v0 = v; i0 = c; }
    else if (b1) { v2 = v1; i2 = i1; v1 = v;  i1 = c; }
    else if (b2) { v2 = v;  i2 = c; }
}

// ---------------------------------------------------------------------------
// Kernel 1: pack sess -> hi-bf16, linear 256 B/row. One wave per row.
// ---------------------------------------------------------------------------
__global__ void pack_sess_kernel(const float* __restrict__ sess,
                                 char* __restrict__ sess2) {
    int row  = blockIdx.x * 4 + (threadIdx.x >> 6);
    int lane = threadIdx.x & 63;
    float2 v = ((const float2*)(sess + (size_t)row * D_DIM))[lane];
    float s = v.x * v.x + v.y * v.y;
    #pragma unroll
    for (int o = 32; o > 0; o >>= 1) s += __shfl_xor(s, o);
    float inv = 1.0f / sqrtf(s + (float)D_DIM * 1e-6f);
    ushort2 hv;
    hv.x = f2bf(v.x * inv);
    hv.y = f2bf(v.y * inv);
    *(ushort2*)(sess2 + (size_t)row * 256 + lane * 4) = hv;
}

// ---------------------------------------------------------------------------
// Kernel 2: pack pool -> 64-row tiles pool2[T2][c<64][slot][16B], XOR-swizzled
// (slot g stored at g^(c&7); c&7 invariant under the 128->64 re-tiling).
// Two-pass, no atomics; per-block dim-sums into S_part[NTP][128].
// ---------------------------------------------------------------------------
__global__ void pack_pool_kernel(const float* __restrict__ pool,
                                 char* __restrict__ pool2,
                                 float* __restrict__ S_part) {
    __shared__ float red[128][17];
    __shared__ float s_inv[128];
    __shared__ float red2[16][128];
    const int tid = threadIdx.x;
    const int T   = blockIdx.x;
    const int c0  = tid >> 4;
    const int g   = tid & 15;

    #pragma unroll
    for (int it = 0; it < 8; ++it) {
        int c = it * 16 + c0;
        int n = T * 128 + c;
        float4 a = make_float4(0.f, 0.f, 0.f, 0.f), b = a;
        if (n < P_ROWS) {
            const float4* src = (const float4*)(pool + (size_t)n * D_DIM + g * 8);
            a = src[0]; b = src[1];
        }
        red[c][g] = a.x*a.x + a.y*a.y + a.z*a.z + a.w*a.w
                  + b.x*b.x + b.y*b.y + b.z*b.z + b.w*b.w;
    }
    __syncthreads();
    if (tid < 128) {
        float s = 0.f;
        #pragma unroll
        for (int j = 0; j < 16; ++j) s += red[tid][j];
        s_inv[tid] = 1.0f / sqrtf(s + (float)D_DIM * 1e-6f);
    }
    __syncthreads();

    float sacc[8] = {0.f,0.f,0.f,0.f,0.f,0.f,0.f,0.f};
    #pragma unroll
    for (int it = 0; it < 8; ++it) {
        int c = it * 16 + c0;
        int n = T * 128 + c;
        float4 a = make_float4(0.f, 0.f, 0.f, 0.f), b = a;
        if (n < P_ROWS) {
            const float4* src = (const float4*)(pool + (size_t)n * D_DIM + g * 8);
            a = src[0]; b = src[1];
        }
        float inv = s_inv[c];
        const float f[8] = {a.x, a.y, a.z, a.w, b.x, b.y, b.z, b.w};
        short8 hv;
        #pragma unroll
        for (int j = 0; j < 8; ++j) {
            float w = f[j] * inv;
            hv[j] = (short)f2bf(w);
            sacc[j] += w;
        }
        int T2 = T * 2 + (c >> 6);          // 64-row tile index
        *(short8*)(pool2 + (size_t)T2 * TILEB + (c & 63) * 256
                   + ((g ^ (c & 7)) * 16)) = hv;
    }
    #pragma unroll
    for (int j = 0; j < 8; ++j) red2[c0][g * 8 + j] = sacc[j];
    __syncthreads();
    if (tid < 128) {
        float s = 0.f;
        #pragma unroll
        for (int k = 0; k < 16; ++k) s += red2[k][tid];
        S_part[(size_t)T * 128 + tid] = s;
    }
}

// ---------------------------------------------------------------------------
// Kernel 2b: reduce S_part[NTP][128] -> S[128]. 128 blocks (one per dim),
// 256 threads each — parallel, ~2 us (R12's single-block version was ~15 us
// on the critical path).
// ---------------------------------------------------------------------------
__global__ void reduce_S_kernel(const float* __restrict__ S_part,
                                float* __restrict__ S) {
    __shared__ float part[256];
    const int d = blockIdx.x;
    float s = 0.f;
    for (int T = threadIdx.x; T < NTP; T += 256)
        s += S_part[(size_t)T * 128 + d];
    part[threadIdx.x] = s;
    __syncthreads();
    #pragma unroll
    for (int o = 128; o > 0; o >>= 1) {
        if (threadIdx.x < o) part[threadIdx.x] += part[threadIdx.x + o];
        __syncthreads();
    }
    if (threadIdx.x == 0) S[d] = part[0];
}

// ---------------------------------------------------------------------------
// Kernel 3: hi-bf16 MFMA cosine SCREEN, top-3 keys only.
// R13: 16 KB B-tiles (64 pool rows) + grid (NPC=128, 16) = 2048 blocks.
// LDS caps residency at 10 blocks/CU, VGPR (~84 combined) at 6 -> ~24
// waves/CU vs R12's 9.6 (32 KB tiles held it to 4-5 blocks/CU, 30% occ,
// latency-bound: no pipe >25% per static count). Per-block work halves;
// chip totals invariant.
// NOTE: launch_bounds stays (256,2) — (256,4) forces a 128-reg budget and
// spills catastrophically (R8: ~850 MB scratch).
// Within-lane key = fp32 v, low 7 mantissa bits := pos = tloc*4+h*2+j (<=51).
// Merge key = u64: monotone(f32 bits)<<32 | (131071-col).
// ---------------------------------------------------------------------------
__launch_bounds__(256, 2)
__global__ void gemm_topk_kernel(const char* __restrict__ sess2,
                                 const char* __restrict__ pool2,
                                 u64* __restrict__ partials) {
    __shared__ char lds[TILEB];

    const int tid = threadIdx.x;
    const int w   = tid >> 6;
    const int L   = tid & 63;
    const int q   = L >> 4;
    const int l15 = L & 15;
    const int l7  = L & 7;
    const int pc  = blockIdx.x;
    const int mt  = blockIdx.y;
    const int rowbase = mt * 128 + w * 32;

    short8 afrag[2][4];
    #pragma unroll
    for (int i = 0; i < 2; ++i)
        #pragma unroll
        for (int ks = 0; ks < 4; ++ks)
            afrag[i][ks] = *(const short8*)(sess2 +
                (size_t)(rowbase + i * 16 + l15) * 256 + (ks * 4 + q) * 16);

    int soks[4];
    #pragma unroll
    for (int ks = 0; ks < 4; ++ks) soks[ks] = ((ks * 4 + q) ^ l7) * 16;
    const char* lbase = lds + l15 * 256;

    float key0[2][4], key1[2][4], key2[2][4];
    #pragma unroll
    for (int i = 0; i < 2; ++i)
        #pragma unroll
        for (int r = 0; r < 4; ++r)
            key0[i][r] = key1[i][r] = key2[i][r] = -1e30f;

    int tloc = 0;
    for (int T = pc; T < NT64; T += NPC, ++tloc) {
        __syncthreads();
        const char* tb = pool2 + (size_t)T * TILEB;
        #pragma unroll
        for (int rr = 0; rr < 4; ++rr) {
            int idx = rr * 256 + tid;
            async16(tb + idx * 16, lds + idx * 16);
        }
        __syncthreads();

        #pragma unroll
        for (int h = 0; h < 2; ++h) {
            f32x4 acc[2][2];
            #pragma unroll
            for (int i = 0; i < 2; ++i) {
                acc[i][0] = (f32x4){0.f,0.f,0.f,0.f};
                acc[i][1] = (f32x4){0.f,0.f,0.f,0.f};
            }
            #pragma unroll
            for (int ks = 0; ks < 4; ++ks) {
                const char* cb = lbase + h * 8192 + soks[ks];
                short8 b0 = *(const short8*)(cb);
                short8 b1 = *(const short8*)(cb + 4096);
                #pragma unroll
                for (int i = 0; i < 2; ++i) {
                    acc[i][0] = __builtin_amdgcn_mfma_f32_16x16x32_bf16(
                        afrag[i][ks], b0, acc[i][0], 0, 0, 0);
                    acc[i][1] = __builtin_amdgcn_mfma_f32_16x16x32_bf16(
                        afrag[i][ks], b1, acc[i][1], 0, 0, 0);
                }
            }
            #pragma unroll
            for (int j = 0; j < 2; ++j) {
                const unsigned pos = (unsigned)(tloc * 4 + h * 2 + j);
                #pragma unroll
                for (int i = 0; i < 2; ++i)
                    #pragma unroll
                    for (int r = 0; r < 4; ++r) {
                        float v = acc[i][j][r];
                        float kf = __uint_as_float(
                            (__float_as_uint(v) & 0xFFFFFF80u) | pos);
                        float o0 = key0[i][r], o1 = key1[i][r];
                        key0[i][r] = fmaxf(o0, kf);
                        key1[i][r] = __builtin_amdgcn_fmed3f(kf, o0, key1[i][r]);
                        key2[i][r] = __builtin_amdgcn_fmed3f(kf, o1, key2[i][r]);
                    }
            }
        }
    }

    // decode -> u64 exact keys, butterfly-merge over the 16 lanes per row
    #pragma unroll
    for (int i = 0; i < 2; ++i)
        #pragma unroll
        for (int r = 0; r < 4; ++r) {
            float kk[3] = {key0[i][r], key1[i][r], key2[i][r]};
            u64 t0 = 0ull, t1 = 0ull, t2 = 0ull;
            #pragma unroll
            for (int k = 0; k < 3; ++k) {
                unsigned u   = __float_as_uint(kk[k]);
                unsigned pos = u & 127u;
                unsigned vb  = u & 0xFFFFFF80u;
                unsigned mono = (vb & 0x80000000u) ? ~vb : (vb | 0x80000000u);
                unsigned col = (unsigned)((pc + (int)(pos >> 2) * NPC) * 64
                                          + (int)(pos & 3u) * 16 + l15);
                u64 key = ((u64)mono << 32) | (u64)(131071u - col);
                kins64(key, t0, t1, t2);
            }
            #pragma unroll
            for (int m = 1; m < 16; m <<= 1) {
                u64 r0 = __shfl_xor(t0, m);
                u64 r1 = __shfl_xor(t1, m);
                u64 r2 = __shfl_xor(t2, m);
                kins64(r0, t0, t1, t2);
                kins64(r1, t0, t1, t2);
                kins64(r2, t0, t1, t2);
            }
            if (l15 == 0) {
                int row = rowbase + i * 16 + q * 4 + r;
                u64* o = partials + ((size_t)row * NPC + pc) * 3;
                o[0] = t0; o[1] = t1; o[2] = t2;
            }
        }
}

// ---------------------------------------------------------------------------
// Kernel 4: per row (one wave) — merge 384 exact-screen u64 keys -> top-8,
// fp64 rescore ONLY those 8, exact top-3 (index tie-break), moment-z,
// double softmax, gather, write. Top-8 extraction fully unrolled (R11).
// ---------------------------------------------------------------------------
__launch_bounds__(256)
__global__ void finalize_kernel(const float* __restrict__ sess,
                                const float* __restrict__ pool,
                                const u64* __restrict__ partials,
                                const float* __restrict__ S,
                                float* __restrict__ out_neighbor,
                                float* __restrict__ out_costopk,
                                float* __restrict__ out_sesstopk) {
    const int row = blockIdx.x * 4 + (threadIdx.x >> 6);
    const int L   = threadIdx.x & 63;

    // 6 keys per lane = 2 chunk-triples (each stored descending)
    const u64* pk = partials + (size_t)row * NCAND + 6 * L;
    u64 t0 = pk[0], t1 = pk[1], t2 = pk[2];
    kins64(pk[3], t0, t1, t2);
    kins64(pk[4], t0, t1, t2);
    kins64(pk[5], t0, t1, t2);

    u64 cand[8];
    #pragma unroll
    for (int k = 0; k < 8; ++k) {
        u64 m = t0;
        #pragma unroll
        for (int o = 1; o < 64; o <<= 1) {
            u64 r = __shfl_xor(m, o);
            m = (r > m) ? r : m;
        }
        cand[k] = m;
        bool pop = (t0 == m);
        t0 = pop ? t1 : t0;
        t1 = pop ? t2 : t1;
        t2 = pop ? 0ull : t2;
    }

    const float2 sa = ((const float2*)(sess + (size_t)row * D_DIM))[L];
    int    idx[8];
    float2 pb[8];
    #pragma unroll
    for (int j = 0; j < 8; ++j) {
        idx[j] = 131071 - (int)(cand[j] & 0x1FFFFull);
        bool ok = idx[j] < P_ROWS;
        pb[j] = ok ? ((const float2*)(pool + (size_t)idx[j] * D_DIM))[L]
                   : make_float2(0.f, 0.f);
    }

    double na  = (double)sa.x * sa.x + (double)sa.y * sa.y;
    double dss = (double)sa.x * S[2 * L] + (double)sa.y * S[2 * L + 1];
    #pragma unroll
    for (int o = 32; o > 0; o >>= 1) {
        na  += __shfl_xor(na, o);
        dss += __shfl_xor(dss, o);
    }
    na += (double)D_DIM * 1e-6;

    double v[8];
    #pragma unroll
    for (int j = 0; j < 8; ++j) {
        double dot = (double)sa.x * pb[j].x + (double)sa.y * pb[j].y;
        double nb  = (double)pb[j].x * pb[j].x + (double)pb[j].y * pb[j].y;
        #pragma unroll
        for (int o = 32; o > 0; o >>= 1) {
            dot += __shfl_xor(dot, o);
            nb  += __shfl_xor(nb, o);
        }
        v[j] = (idx[j] < P_ROWS)
             ? dot / sqrt(na * (nb + (double)D_DIM * 1e-6))
             : -1e300;
    }

    double v0 = -1e300, v1 = -1e300, v2 = -1e300;
    int    i0 = 0x7fffffff, i1 = 0x7fffffff, i2 = 0x7fffffff;
    #pragma unroll
    for (int j = 0; j < 8; ++j) ins3d(v[j], idx[j], v0, i0, v1, i1, v2, i2);

    double z  = (double)P_ROWS + dss / sqrt(na) + 390.625;
    double c0 = exp(v0) / z, c1 = exp(v1) / z, c2 = exp(v2) / z;
    double e1 = exp(c1 - c0), e2 = exp(c2 - c0);
    double inv = 1.0 / (1.0 + e1 + e2);
    float  w0 = (float)inv, w1 = (float)(e1 * inv), w2 = (float)(e2 * inv);

    float2 g0 = ((const float2*)(pool + (size_t)i0 * D_DIM))[L];
    float2 g1 = ((const float2*)(pool + (size_t)i1 * D_DIM))[L];
    float2 g2 = ((const float2*)(pool + (size_t)i2 * D_DIM))[L];
    ((float2*)(out_sesstopk + ((size_t)row * 3 + 0) * D_DIM))[L] = g0;
    ((float2*)(out_sesstopk + ((size_t)row * 3 + 1) * D_DIM))[L] = g1;
    ((float2*)(out_sesstopk + ((size_t)row * 3 + 2) * D_DIM))[L] = g2;
    float2 nbv;
    nbv.x = w0 * g0.x + w1 * g1.x + w2 * g2.x;
    nbv.y = w0 * g0.y + w1 * g1.y + w2 * g2.y;
    ((float2*)(out_neighbor + (size_t)row * D_DIM))[L] = nbv;
    if (L == 0) {
        out_costopk[row * 3 + 0] = w0;
        out_costopk[row * 3 + 1] = w1;
        out_costopk[row * 3 + 2] = w2;
    }
}

// ---------------------------------------------------------------------------
extern "C" void kernel_launch(void* const* d_in, const int* in_sizes, int n_in,
                              void* d_out, int out_size, void* d_ws, size_t ws_size,
                              hipStream_t stream) {
    const float* sess = (const float*)d_in[0];   // [2048,128]
    const float* pool = (const float*)d_in[1];   // [100000,128]
    float* out = (float*)d_out;
    float* out_neighbor = out;
    float* out_costopk  = out + (size_t)B_ROWS * D_DIM;
    float* out_sesstopk = out_costopk + (size_t)B_ROWS * 3;

    // ws: S(512B) | S_part(400KB) | partials(6.3MB) | sess2(512KB) |
    //     pool2(1564*16KB = 25.6MB; tile 1563 is write-only padding)
    float* Svec     = (float*)d_ws;
    float* S_part   = (float*)((char*)d_ws + 512);
    u64*   partials = (u64*)((char*)d_ws + 512 + (size_t)NTP * 128 * 4);
    char*  sess2    = (char*)partials + (size_t)B_ROWS * NCAND * 8;
    char*  pool2    = sess2 + (size_t)B_ROWS * 256;

    pack_sess_kernel<<<B_ROWS / 4, 256, 0, stream>>>(sess, sess2);
    pack_pool_kernel<<<NTP, 256, 0, stream>>>(pool, pool2, S_part);
    reduce_S_kernel<<<128, 256, 0, stream>>>(S_part, Svec);

    dim3 g3(NPC, B_ROWS / 128);
    gemm_topk_kernel<<<g3, 256, 0, stream>>>(sess2, pool2, partials);

    finalize_kernel<<<B_ROWS / 4, 256, 0, stream>>>(
        sess, pool, partials, Svec, out_neighbor, out_costopk, out_sesstopk);
}

// Round 14
// 201.883 us; speedup vs baseline: 1.0908x; 1.0580x over previous
//
#include <hip/hip_runtime.h>
#include <math.h>

#define B_ROWS 2048
#define P_ROWS 100000
#define D_DIM  128
#define NPC    64                 // pool chunks (grid.x of gemm)
#define NT     782                // 128-row pool tiles
#define TILEB  32768              // 128 pool-rows x 128 bf16 (256 B/row)
#define NCAND  (NPC * 3)          // 192 screened candidates per row

typedef short short8 __attribute__((ext_vector_type(8)));
typedef float f32x4  __attribute__((ext_vector_type(4)));
typedef unsigned long long u64;

// bf16 RNE
__device__ __forceinline__ unsigned short f2bf(float f) {
    unsigned u = __float_as_uint(f);
    u += 0x7fffu + ((u >> 16) & 1u);
    return (unsigned short)(u >> 16);
}

__device__ __forceinline__ void async16(const char* g, char* l) {
    __builtin_amdgcn_global_load_lds(
        (const __attribute__((address_space(1))) unsigned int*)g,
        (__attribute__((address_space(3))) unsigned int*)l,
        16, 0, 0);
}

// u64 branchless top-3 insert
__device__ __forceinline__ void kins64(u64 k, u64& t0, u64& t1, u64& t2) {
    u64 m0 = (t0 < k) ? t0 : k;  t0 = (t0 < k) ? k : t0;
    u64 m1 = (t1 < m0) ? t1 : m0; t1 = (t1 < m0) ? m0 : t1;
    t2 = (t2 < m1) ? m1 : t2;
}

// fp64 top-3 insert with index tie-break (lower index wins)
__device__ __forceinline__ void ins3d(double v, int c,
                                      double& v0, int& i0,
                                      double& v1, int& i1,
                                      double& v2, int& i2) {
    bool b0 = (v > v0) || (v == v0 && c < i0);
    bool b1 = (v > v1) || (v == v1 && c < i1);
    bool b2 = (v > v2) || (v == v2 && c < i2);
    if (b0)      { v2 = v1; i2 = i1; v1 = v0; i1 = i0; v0 = v; i0 = c; }
    else if (b1) { v2 = v1; i2 = i1; v1 = v;  i1 = c; }
    else if (b2) { v2 = v;  i2 = c; }
}

// ---------------------------------------------------------------------------
// Kernel 1: pack sess -> hi-bf16, linear 256 B/row. One wave per row.
// ---------------------------------------------------------------------------
__global__ void pack_sess_kernel(const float* __restrict__ sess,
                                 char* __restrict__ sess2) {
    int row  = blockIdx.x * 4 + (threadIdx.x >> 6);
    int lane = threadIdx.x & 63;
    float2 v = ((const float2*)(sess + (size_t)row * D_DIM))[lane];
    float s = v.x * v.x + v.y * v.y;
    #pragma unroll
    for (int o = 32; o > 0; o >>= 1) s += __shfl_xor(s, o);
    float inv = 1.0f / sqrtf(s + (float)D_DIM * 1e-6f);
    ushort2 hv;
    hv.x = f2bf(v.x * inv);
    hv.y = f2bf(v.y * inv);
    *(ushort2*)(sess2 + (size_t)row * 256 + lane * 4) = hv;
}

// ---------------------------------------------------------------------------
// Kernel 2: pack pool -> pool2[T][c][slot][16B] hi-bf16, XOR-swizzled.
// Two-pass, no atomics; per-block dim-sums into S_part[NT][128].
// ---------------------------------------------------------------------------
__global__ void pack_pool_kernel(const float* __restrict__ pool,
                                 char* __restrict__ pool2,
                                 float* __restrict__ S_part) {
    __shared__ float red[128][17];
    __shared__ float s_inv[128];
    __shared__ float red2[16][128];
    const int tid = threadIdx.x;
    const int T   = blockIdx.x;
    const int c0  = tid >> 4;
    const int g   = tid & 15;

    #pragma unroll
    for (int it = 0; it < 8; ++it) {
        int c = it * 16 + c0;
        int n = T * 128 + c;
        float4 a = make_float4(0.f, 0.f, 0.f, 0.f), b = a;
        if (n < P_ROWS) {
            const float4* src = (const float4*)(pool + (size_t)n * D_DIM + g * 8);
            a = src[0]; b = src[1];
        }
        red[c][g] = a.x*a.x + a.y*a.y + a.z*a.z + a.w*a.w
                  + b.x*b.x + b.y*b.y + b.z*b.z + b.w*b.w;
    }
    __syncthreads();
    if (tid < 128) {
        float s = 0.f;
        #pragma unroll
        for (int j = 0; j < 16; ++j) s += red[tid][j];
        s_inv[tid] = 1.0f / sqrtf(s + (float)D_DIM * 1e-6f);
    }
    __syncthreads();

    float sacc[8] = {0.f,0.f,0.f,0.f,0.f,0.f,0.f,0.f};
    #pragma unroll
    for (int it = 0; it < 8; ++it) {
        int c = it * 16 + c0;
        int n = T * 128 + c;
        float4 a = make_float4(0.f, 0.f, 0.f, 0.f), b = a;
        if (n < P_ROWS) {
            const float4* src = (const float4*)(pool + (size_t)n * D_DIM + g * 8);
            a = src[0]; b = src[1];
        }
        float inv = s_inv[c];
        const float f[8] = {a.x, a.y, a.z, a.w, b.x, b.y, b.z, b.w};
        short8 hv;
        #pragma unroll
        for (int j = 0; j < 8; ++j) {
            float w = f[j] * inv;
            hv[j] = (short)f2bf(w);
            sacc[j] += w;
        }
        *(short8*)(pool2 + (size_t)T * TILEB + c * 256 + ((g ^ (c & 7)) * 16)) = hv;
    }
    #pragma unroll
    for (int j = 0; j < 8; ++j) red2[c0][g * 8 + j] = sacc[j];
    __syncthreads();
    if (tid < 128) {
        float s = 0.f;
        #pragma unroll
        for (int k = 0; k < 16; ++k) s += red2[k][tid];
        S_part[(size_t)T * 128 + tid] = s;
    }
}

// ---------------------------------------------------------------------------
// Kernel 2b: reduce S_part[NT][128] -> S[128]. 128 blocks (one per dim).
// ---------------------------------------------------------------------------
__global__ void reduce_S_kernel(const float* __restrict__ S_part,
                                float* __restrict__ S) {
    __shared__ float part[256];
    const int d = blockIdx.x;
    float s = 0.f;
    for (int T = threadIdx.x; T < NT; T += 256)
        s += S_part[(size_t)T * 128 + d];
    part[threadIdx.x] = s;
    __syncthreads();
    #pragma unroll
    for (int o = 128; o > 0; o >>= 1) {
        if (threadIdx.x < o) part[threadIdx.x] += part[threadIdx.x + o];
        __syncthreads();
    }
    if (threadIdx.x == 0) S[d] = part[0];
}

// ---------------------------------------------------------------------------
// Kernel 3: hi-bf16 MFMA cosine SCREEN, top-3 keys only. Identical to R12
// (93 us best). Grid (64,16)=1024 blocks; 32 KB tiles; 32 rows/wave.
// NOTE: launch_bounds stays (256,2) — (256,4) spills ~850 MB (R8).
// ---------------------------------------------------------------------------
__launch_bounds__(256, 2)
__global__ void gemm_topk_kernel(const char* __restrict__ sess2,
                                 const char* __restrict__ pool2,
                                 u64* __restrict__ partials) {
    __shared__ char lds[TILEB];

    const int tid = threadIdx.x;
    const int w   = tid >> 6;
    const int L   = tid & 63;
    const int q   = L >> 4;
    const int l15 = L & 15;
    const int l7  = L & 7;
    const int pc  = blockIdx.x;
    const int mt  = blockIdx.y;
    const int rowbase = mt * 128 + w * 32;

    short8 afrag[2][4];
    #pragma unroll
    for (int i = 0; i < 2; ++i)
        #pragma unroll
        for (int ks = 0; ks < 4; ++ks)
            afrag[i][ks] = *(const short8*)(sess2 +
                (size_t)(rowbase + i * 16 + l15) * 256 + (ks * 4 + q) * 16);

    int soks[4];
    #pragma unroll
    for (int ks = 0; ks < 4; ++ks) soks[ks] = ((ks * 4 + q) ^ l7) * 16;
    const char* lbase = lds + l15 * 256;

    float key0[2][4], key1[2][4], key2[2][4];
    #pragma unroll
    for (int i = 0; i < 2; ++i)
        #pragma unroll
        for (int r = 0; r < 4; ++r)
            key0[i][r] = key1[i][r] = key2[i][r] = -1e30f;

    int tloc = 0;
    for (int T = pc; T < NT; T += NPC, ++tloc) {
        __syncthreads();
        const char* tb = pool2 + (size_t)T * TILEB;
        #pragma unroll
        for (int rr = 0; rr < 8; ++rr) {
            int idx = rr * 256 + tid;
            async16(tb + idx * 16, lds + idx * 16);
        }
        __syncthreads();

        #pragma unroll
        for (int qt = 0; qt < 4; ++qt) {
            f32x4 acc[2][2];
            #pragma unroll
            for (int i = 0; i < 2; ++i) {
                acc[i][0] = (f32x4){0.f,0.f,0.f,0.f};
                acc[i][1] = (f32x4){0.f,0.f,0.f,0.f};
            }
            #pragma unroll
            for (int ks = 0; ks < 4; ++ks) {
                const char* cb = lbase + qt * 8192 + soks[ks];
                short8 b0 = *(const short8*)(cb);
                short8 b1 = *(const short8*)(cb + 16 * 256);
                #pragma unroll
                for (int i = 0; i < 2; ++i) {
                    acc[i][0] = __builtin_amdgcn_mfma_f32_16x16x32_bf16(
                        afrag[i][ks], b0, acc[i][0], 0, 0, 0);
                    acc[i][1] = __builtin_amdgcn_mfma_f32_16x16x32_bf16(
                        afrag[i][ks], b1, acc[i][1], 0, 0, 0);
                }
            }
            #pragma unroll
            for (int j = 0; j < 2; ++j) {
                const unsigned pos = (unsigned)(tloc * 8 + qt * 2 + j);
                #pragma unroll
                for (int i = 0; i < 2; ++i)
                    #pragma unroll
                    for (int r = 0; r < 4; ++r) {
                        float v = acc[i][j][r];
                        float kf = __uint_as_float(
                            (__float_as_uint(v) & 0xFFFFFF80u) | pos);
                        float o0 = key0[i][r], o1 = key1[i][r];
                        key0[i][r] = fmaxf(o0, kf);
                        key1[i][r] = __builtin_amdgcn_fmed3f(kf, o0, key1[i][r]);
                        key2[i][r] = __builtin_amdgcn_fmed3f(kf, o1, key2[i][r]);
                    }
            }
        }
    }

    #pragma unroll
    for (int i = 0; i < 2; ++i)
        #pragma unroll
        for (int r = 0; r < 4; ++r) {
            float kk[3] = {key0[i][r], key1[i][r], key2[i][r]};
            u64 t0 = 0ull, t1 = 0ull, t2 = 0ull;
            #pragma unroll
            for (int k = 0; k < 3; ++k) {
                unsigned u   = __float_as_uint(kk[k]);
                unsigned pos = u & 127u;
                unsigned vb  = u & 0xFFFFFF80u;
                unsigned mono = (vb & 0x80000000u) ? ~vb : (vb | 0x80000000u);
                unsigned col = (unsigned)((pc + (int)(pos >> 3) * NPC) * 128
                                          + (int)(pos & 7u) * 16 + l15);
                u64 key = ((u64)mono << 32) | (u64)(131071u - col);
                kins64(key, t0, t1, t2);
            }
            #pragma unroll
            for (int m = 1; m < 16; m <<= 1) {
                u64 r0 = __shfl_xor(t0, m);
                u64 r1 = __shfl_xor(t1, m);
                u64 r2 = __shfl_xor(t2, m);
                kins64(r0, t0, t1, t2);
                kins64(r1, t0, t1, t2);
                kins64(r2, t0, t1, t2);
            }
            if (l15 == 0) {
                int row = rowbase + i * 16 + q * 4 + r;
                u64* o = partials + ((size_t)row * NPC + pc) * 3;
                o[0] = t0; o[1] = t1; o[2] = t2;
            }
        }
}

// ---------------------------------------------------------------------------
// Kernel 4 (R14 rewrite): one row per block, ZERO indexed register arrays —
// all staging through LDS. R10 evidence: per-thread arrays (cand[8]/pb[8])
// went to scratch -> runtime throttled residency to 0.5% occupancy ->
// ~100-120 us latency-bound. This version cannot spill.
//   w3: na/dss butterfly -> LDS.  w0: 8x (LDS scan + butterfly max + zero
//   owner) -> top8 in LDS.  each wave rescores 2 candidates (fp64, scalar).
//   lane 0: exact top-3 + weights.  all: output write.
// ---------------------------------------------------------------------------
__launch_bounds__(256)
__global__ void finalize_kernel(const float* __restrict__ sess,
                                const float* __restrict__ pool,
                                const u64* __restrict__ partials,
                                const float* __restrict__ S,
                                float* __restrict__ out_neighbor,
                                float* __restrict__ out_costopk,
                                float* __restrict__ out_sesstopk) {
    __shared__ u64    keys[NCAND];
    __shared__ u64    top8[8];
    __shared__ double vv[8];
    __shared__ int    ii[8];
    __shared__ double s_na, s_dss;
    __shared__ float  s_w[3];
    __shared__ int    s_i[3];

    const int row = blockIdx.x;
    const int tid = threadIdx.x;
    const int w   = tid >> 6;
    const int L   = tid & 63;

    // stage keys (threads 0..191); wave 3 computes na & dss meanwhile
    if (tid < NCAND) keys[tid] = partials[(size_t)row * NCAND + tid];
    if (w == 3) {
        float2 sa = ((const float2*)(sess + (size_t)row * D_DIM))[L];
        double na  = (double)sa.x * sa.x + (double)sa.y * sa.y;
        double dss = (double)sa.x * S[2 * L] + (double)sa.y * S[2 * L + 1];
        #pragma unroll
        for (int o = 32; o > 0; o >>= 1) {
            na  += __shfl_xor(na, o);
            dss += __shfl_xor(dss, o);
        }
        if (L == 0) { s_na = na + (double)D_DIM * 1e-6; s_dss = dss; }
    }
    __syncthreads();

    // wave 0: extract top-8 (keys unique via col bits; zeros only padding)
    if (w == 0) {
        for (int k = 0; k < 8; ++k) {
            u64 a0 = keys[L], a1 = keys[L + 64], a2 = keys[L + 128];
            u64 m = a0 > a1 ? a0 : a1;
            m = m > a2 ? m : a2;
            u64 g = m;
            #pragma unroll
            for (int o = 1; o < 64; o <<= 1) {
                u64 r = __shfl_xor(g, o);
                g = (r > g) ? r : g;
            }
            if (m == g && g != 0ull) {
                if (a0 == g)      keys[L] = 0ull;
                else if (a1 == g) keys[L + 64] = 0ull;
                else              keys[L + 128] = 0ull;
            }
            if (L == 0) top8[k] = g;
        }
    }
    __syncthreads();

    // each wave rescores candidates 2w and 2w+1 in fp64 (all scalars)
    {
        float2 sa = ((const float2*)(sess + (size_t)row * D_DIM))[L];
        for (int cc = 0; cc < 2; ++cc) {
            int c = 2 * w + cc;
            int idx = 131071 - (int)(top8[c] & 0x1FFFFull);
            bool ok = idx < P_ROWS;
            float2 pb = ok ? ((const float2*)(pool + (size_t)idx * D_DIM))[L]
                           : make_float2(0.f, 0.f);
            double dot = (double)sa.x * pb.x + (double)sa.y * pb.y;
            double nb  = (double)pb.x * pb.x + (double)pb.y * pb.y;
            #pragma unroll
            for (int o = 32; o > 0; o >>= 1) {
                dot += __shfl_xor(dot, o);
                nb  += __shfl_xor(nb, o);
            }
            if (L == 0) {
                vv[c] = ok ? dot / sqrt(s_na * (nb + (double)D_DIM * 1e-6))
                           : -1e300;
                ii[c] = idx;
            }
        }
    }
    __syncthreads();

    // lane 0: exact top-3 of 8 + weights
    if (tid == 0) {
        double v0 = -1e300, v1 = -1e300, v2 = -1e300;
        int    i0 = 0x7fffffff, i1 = 0x7fffffff, i2 = 0x7fffffff;
        for (int j = 0; j < 8; ++j) ins3d(vv[j], ii[j], v0, i0, v1, i1, v2, i2);
        double z  = (double)P_ROWS + s_dss / sqrt(s_na) + 390.625;
        double c0 = exp(v0) / z, c1 = exp(v1) / z, c2 = exp(v2) / z;
        double e1 = exp(c1 - c0), e2 = exp(c2 - c0);
        double inv = 1.0 / (1.0 + e1 + e2);
        s_w[0] = (float)inv;
        s_w[1] = (float)(e1 * inv);
        s_w[2] = (float)(e2 * inv);
        s_i[0] = i0; s_i[1] = i1; s_i[2] = i2;
    }
    __syncthreads();

    if (tid < D_DIM) {
        float g0 = pool[(size_t)s_i[0] * D_DIM + tid];
        float g1 = pool[(size_t)s_i[1] * D_DIM + tid];
        float g2 = pool[(size_t)s_i[2] * D_DIM + tid];
        out_sesstopk[((size_t)row * 3 + 0) * D_DIM + tid] = g0;
        out_sesstopk[((size_t)row * 3 + 1) * D_DIM + tid] = g1;
        out_sesstopk[((size_t)row * 3 + 2) * D_DIM + tid] = g2;
        out_neighbor[(size_t)row * D_DIM + tid] =
            s_w[0] * g0 + s_w[1] * g1 + s_w[2] * g2;
        if (tid < 3) out_costopk[row * 3 + tid] = s_w[tid];
    }
}

// ---------------------------------------------------------------------------
extern "C" void kernel_launch(void* const* d_in, const int* in_sizes, int n_in,
                              void* d_out, int out_size, void* d_ws, size_t ws_size,
                              hipStream_t stream) {
    const float* sess = (const float*)d_in[0];   // [2048,128]
    const float* pool = (const float*)d_in[1];   // [100000,128]
    float* out = (float*)d_out;
    float* out_neighbor = out;
    float* out_costopk  = out + (size_t)B_ROWS * D_DIM;
    float* out_sesstopk = out_costopk + (size_t)B_ROWS * 3;

    // ws: S(512B) | S_part(400KB) | partials(3.1MB) | sess2(512KB) | pool2(25.6MB)
    float* Svec     = (float*)d_ws;
    float* S_part   = (float*)((char*)d_ws + 512);
    u64*   partials = (u64*)((char*)d_ws + 512 + (size_t)NT * 128 * 4);
    char*  sess2    = (char*)partials + (size_t)B_ROWS * NCAND * 8;
    char*  pool2    = sess2 + (size_t)B_ROWS * 256;

    pack_sess_kernel<<<B_ROWS / 4, 256, 0, stream>>>(sess, sess2);
    pack_pool_kernel<<<NT, 256, 0, stream>>>(pool, pool2, S_part);
    reduce_S_kernel<<<128, 256, 0, stream>>>(S_part, Svec);

    dim3 g3(NPC, B_ROWS / 128);
    gemm_topk_kernel<<<g3, 256, 0, stream>>>(sess2, pool2, partials);

    finalize_kernel<<<B_ROWS, 256, 0, stream>>>(
        sess, pool, partials, Svec, out_neighbor, out_costopk, out_sesstopk);
}

// Round 15
// 194.895 us; speedup vs baseline: 1.1300x; 1.0359x over previous
//
#include <hip/hip_runtime.h>
#include <math.h>

#define B_ROWS 2048
#define P_ROWS 100000
#define D_DIM  128
#define NPC    64                 // pool chunks (grid.x of gemm)
#define NT     782                // 128-row pool tiles
#define TILEB  32768              // 128 pool-rows x 128 bf16 (256 B/row)
#define NCAND  (NPC * 3)          // 192 screened candidates per row

typedef short short8 __attribute__((ext_vector_type(8)));
typedef float f32x4  __attribute__((ext_vector_type(4)));
typedef unsigned long long u64;

// bf16 RNE
__device__ __forceinline__ unsigned short f2bf(float f) {
    unsigned u = __float_as_uint(f);
    u += 0x7fffu + ((u >> 16) & 1u);
    return (unsigned short)(u >> 16);
}

__device__ __forceinline__ void async16(const char* g, char* l) {
    __builtin_amdgcn_global_load_lds(
        (const __attribute__((address_space(1))) unsigned int*)g,
        (__attribute__((address_space(3))) unsigned int*)l,
        16, 0, 0);
}

// u64 branchless top-3 insert
__device__ __forceinline__ void kins64(u64 k, u64& t0, u64& t1, u64& t2) {
    u64 m0 = (t0 < k) ? t0 : k;  t0 = (t0 < k) ? k : t0;
    u64 m1 = (t1 < m0) ? t1 : m0; t1 = (t1 < m0) ? m0 : t1;
    t2 = (t2 < m1) ? m1 : t2;
}

// fp64 top-3 insert with index tie-break (lower index wins)
__device__ __forceinline__ void ins3d(double v, int c,
                                      double& v0, int& i0,
                                      double& v1, int& i1,
                                      double& v2, int& i2) {
    bool b0 = (v > v0) || (v == v0 && c < i0);
    bool b1 = (v > v1) || (v == v1 && c < i1);
    bool b2 = (v > v2) || (v == v2 && c < i2);
    if (b0)      { v2 = v1; i2 = i1; v1 = v0; i1 = i0; v0 = v; i0 = c; }
    else if (b1) { v2 = v1; i2 = i1; v1 = v;  i1 = c; }
    else if (b2) { v2 = v;  i2 = c; }
}

// ---------------------------------------------------------------------------
// Kernel 1 (R15 merged): blocks [0,NT) pack pool; blocks [NT,NT+512) pack
// sess. Pool path is SINGLE-PASS: row norm via 4-step shfl_xor inside the
// 16-lane row group (no LDS round-trip, no barrier; R14's two-pass version
// re-read 51 MB and held 64 VGPRs across barriers). One barrier at the end
// for the per-block S partial.
// ---------------------------------------------------------------------------
__global__ void pack_kernel(const float* __restrict__ sess,
                            const float* __restrict__ pool,
                            char* __restrict__ sess2,
                            char* __restrict__ pool2,
                            float* __restrict__ S_part) {
    const int tid = threadIdx.x;
    const int bx  = blockIdx.x;

    if (bx >= NT) {               // ---- sess path: one wave per row ----
        int row  = (bx - NT) * 4 + (tid >> 6);
        int lane = tid & 63;
        float2 v = ((const float2*)(sess + (size_t)row * D_DIM))[lane];
        float s = v.x * v.x + v.y * v.y;
        #pragma unroll
        for (int o = 32; o > 0; o >>= 1) s += __shfl_xor(s, o);
        float inv = 1.0f / sqrtf(s + (float)D_DIM * 1e-6f);
        ushort2 hv;
        hv.x = f2bf(v.x * inv);
        hv.y = f2bf(v.y * inv);
        *(ushort2*)(sess2 + (size_t)row * 256 + lane * 4) = hv;
        return;
    }

    // ---- pool path ----
    __shared__ float red2[16][128];
    const int T  = bx;
    const int c0 = tid >> 4;      // row-in-iteration (16 rows/iter)
    const int g  = tid & 15;      // 8-elem group within the row

    float sacc[8] = {0.f,0.f,0.f,0.f,0.f,0.f,0.f,0.f};
    #pragma unroll
    for (int it = 0; it < 8; ++it) {
        int c = it * 16 + c0;
        int n = T * 128 + c;
        float4 a = make_float4(0.f, 0.f, 0.f, 0.f), b = a;
        if (n < P_ROWS) {
            const float4* src = (const float4*)(pool + (size_t)n * D_DIM + g * 8);
            a = src[0]; b = src[1];
        }
        float s = a.x*a.x + a.y*a.y + a.z*a.z + a.w*a.w
                + b.x*b.x + b.y*b.y + b.z*b.z + b.w*b.w;
        // row-sum across the 16 lanes owning row c (aligned 16-lane group)
        s += __shfl_xor(s, 1);
        s += __shfl_xor(s, 2);
        s += __shfl_xor(s, 4);
        s += __shfl_xor(s, 8);
        float inv = 1.0f / sqrtf(s + (float)D_DIM * 1e-6f);
        const float f[8] = {a.x, a.y, a.z, a.w, b.x, b.y, b.z, b.w};
        short8 hv;
        #pragma unroll
        for (int j = 0; j < 8; ++j) {
            float w = f[j] * inv;
            hv[j] = (short)f2bf(w);
            sacc[j] += w;
        }
        *(short8*)(pool2 + (size_t)T * TILEB + c * 256 + ((g ^ (c & 7)) * 16)) = hv;
    }
    #pragma unroll
    for (int j = 0; j < 8; ++j) red2[c0][g * 8 + j] = sacc[j];
    __syncthreads();
    if (tid < 128) {
        float s = 0.f;
        #pragma unroll
        for (int k = 0; k < 16; ++k) s += red2[k][tid];
        S_part[(size_t)T * 128 + tid] = s;
    }
}

// ---------------------------------------------------------------------------
// Kernel 2: hi-bf16 MFMA cosine SCREEN (R12 body, 93 us) + fused reduce_S:
// grid (NPC, 17); blocks with mt==16 (64 of them) reduce S_part -> S (2 dims
// each) concurrently with the gemm blocks, saving a separate launch. LDS for
// the reduction aliases the gemm tile buffer (no LDS growth).
// NOTE: launch_bounds stays (256,2) — (256,4) spills ~850 MB (R8).
// ---------------------------------------------------------------------------
__launch_bounds__(256, 2)
__global__ void gemm_topk_kernel(const char* __restrict__ sess2,
                                 const char* __restrict__ pool2,
                                 u64* __restrict__ partials,
                                 const float* __restrict__ S_part,
                                 float* __restrict__ S) {
    __shared__ char lds[TILEB];

    const int tid = threadIdx.x;
    const int pc  = blockIdx.x;
    const int mt  = blockIdx.y;

    if (mt == 16) {               // ---- reduce_S path: 64 blocks, 2 dims each
        float* part = (float*)lds;
        #pragma unroll
        for (int d2 = 0; d2 < 2; ++d2) {
            int d = pc * 2 + d2;
            float s = 0.f;
            for (int T = tid; T < NT; T += 256)
                s += S_part[(size_t)T * 128 + d];
            part[tid] = s;
            __syncthreads();
            for (int o = 128; o > 0; o >>= 1) {
                if (tid < o) part[tid] += part[tid + o];
                __syncthreads();
            }
            if (tid == 0) S[d] = part[0];
            __syncthreads();
        }
        return;
    }

    const int w   = tid >> 6;
    const int L   = tid & 63;
    const int q   = L >> 4;
    const int l15 = L & 15;
    const int l7  = L & 7;
    const int rowbase = mt * 128 + w * 32;

    short8 afrag[2][4];
    #pragma unroll
    for (int i = 0; i < 2; ++i)
        #pragma unroll
        for (int ks = 0; ks < 4; ++ks)
            afrag[i][ks] = *(const short8*)(sess2 +
                (size_t)(rowbase + i * 16 + l15) * 256 + (ks * 4 + q) * 16);

    int soks[4];
    #pragma unroll
    for (int ks = 0; ks < 4; ++ks) soks[ks] = ((ks * 4 + q) ^ l7) * 16;
    const char* lbase = lds + l15 * 256;

    float key0[2][4], key1[2][4], key2[2][4];
    #pragma unroll
    for (int i = 0; i < 2; ++i)
        #pragma unroll
        for (int r = 0; r < 4; ++r)
            key0[i][r] = key1[i][r] = key2[i][r] = -1e30f;

    int tloc = 0;
    for (int T = pc; T < NT; T += NPC, ++tloc) {
        __syncthreads();
        const char* tb = pool2 + (size_t)T * TILEB;
        #pragma unroll
        for (int rr = 0; rr < 8; ++rr) {
            int idx = rr * 256 + tid;
            async16(tb + idx * 16, lds + idx * 16);
        }
        __syncthreads();

        #pragma unroll
        for (int qt = 0; qt < 4; ++qt) {
            f32x4 acc[2][2];
            #pragma unroll
            for (int i = 0; i < 2; ++i) {
                acc[i][0] = (f32x4){0.f,0.f,0.f,0.f};
                acc[i][1] = (f32x4){0.f,0.f,0.f,0.f};
            }
            #pragma unroll
            for (int ks = 0; ks < 4; ++ks) {
                const char* cb = lbase + qt * 8192 + soks[ks];
                short8 b0 = *(const short8*)(cb);
                short8 b1 = *(const short8*)(cb + 16 * 256);
                #pragma unroll
                for (int i = 0; i < 2; ++i) {
                    acc[i][0] = __builtin_amdgcn_mfma_f32_16x16x32_bf16(
                        afrag[i][ks], b0, acc[i][0], 0, 0, 0);
                    acc[i][1] = __builtin_amdgcn_mfma_f32_16x16x32_bf16(
                        afrag[i][ks], b1, acc[i][1], 0, 0, 0);
                }
            }
            #pragma unroll
            for (int j = 0; j < 2; ++j) {
                const unsigned pos = (unsigned)(tloc * 8 + qt * 2 + j);
                #pragma unroll
                for (int i = 0; i < 2; ++i)
                    #pragma unroll
                    for (int r = 0; r < 4; ++r) {
                        float v = acc[i][j][r];
                        float kf = __uint_as_float(
                            (__float_as_uint(v) & 0xFFFFFF80u) | pos);
                        float o0 = key0[i][r], o1 = key1[i][r];
                        key0[i][r] = fmaxf(o0, kf);
                        key1[i][r] = __builtin_amdgcn_fmed3f(kf, o0, key1[i][r]);
                        key2[i][r] = __builtin_amdgcn_fmed3f(kf, o1, key2[i][r]);
                    }
            }
        }
    }

    #pragma unroll
    for (int i = 0; i < 2; ++i)
        #pragma unroll
        for (int r = 0; r < 4; ++r) {
            float kk[3] = {key0[i][r], key1[i][r], key2[i][r]};
            u64 t0 = 0ull, t1 = 0ull, t2 = 0ull;
            #pragma unroll
            for (int k = 0; k < 3; ++k) {
                unsigned u   = __float_as_uint(kk[k]);
                unsigned pos = u & 127u;
                unsigned vb  = u & 0xFFFFFF80u;
                unsigned mono = (vb & 0x80000000u) ? ~vb : (vb | 0x80000000u);
                unsigned col = (unsigned)((pc + (int)(pos >> 3) * NPC) * 128
                                          + (int)(pos & 7u) * 16 + l15);
                u64 key = ((u64)mono << 32) | (u64)(131071u - col);
                kins64(key, t0, t1, t2);
            }
            #pragma unroll
            for (int m = 1; m < 16; m <<= 1) {
                u64 r0 = __shfl_xor(t0, m);
                u64 r1 = __shfl_xor(t1, m);
                u64 r2 = __shfl_xor(t2, m);
                kins64(r0, t0, t1, t2);
                kins64(r1, t0, t1, t2);
                kins64(r2, t0, t1, t2);
            }
            if (l15 == 0) {
                int row = rowbase + i * 16 + q * 4 + r;
                u64* o = partials + ((size_t)row * NPC + pc) * 3;
                o[0] = t0; o[1] = t1; o[2] = t2;
            }
        }
}

// ---------------------------------------------------------------------------
// Kernel 3: one row per block, zero indexed register arrays (R14).
// ---------------------------------------------------------------------------
__launch_bounds__(256)
__global__ void finalize_kernel(const float* __restrict__ sess,
                                const float* __restrict__ pool,
                                const u64* __restrict__ partials,
                                const float* __restrict__ S,
                                float* __restrict__ out_neighbor,
                                float* __restrict__ out_costopk,
                                float* __restrict__ out_sesstopk) {
    __shared__ u64    keys[NCAND];
    __shared__ u64    top8[8];
    __shared__ double vv[8];
    __shared__ int    ii[8];
    __shared__ double s_na, s_dss;
    __shared__ float  s_w[3];
    __shared__ int    s_i[3];

    const int row = blockIdx.x;
    const int tid = threadIdx.x;
    const int w   = tid >> 6;
    const int L   = tid & 63;

    if (tid < NCAND) keys[tid] = partials[(size_t)row * NCAND + tid];
    if (w == 3) {
        float2 sa = ((const float2*)(sess + (size_t)row * D_DIM))[L];
        double na  = (double)sa.x * sa.x + (double)sa.y * sa.y;
        double dss = (double)sa.x * S[2 * L] + (double)sa.y * S[2 * L + 1];
        #pragma unroll
        for (int o = 32; o > 0; o >>= 1) {
            na  += __shfl_xor(na, o);
            dss += __shfl_xor(dss, o);
        }
        if (L == 0) { s_na = na + (double)D_DIM * 1e-6; s_dss = dss; }
    }
    __syncthreads();

    if (w == 0) {
        for (int k = 0; k < 8; ++k) {
            u64 a0 = keys[L], a1 = keys[L + 64], a2 = keys[L + 128];
            u64 m = a0 > a1 ? a0 : a1;
            m = m > a2 ? m : a2;
            u64 g = m;
            #pragma unroll
            for (int o = 1; o < 64; o <<= 1) {
                u64 r = __shfl_xor(g, o);
                g = (r > g) ? r : g;
            }
            if (m == g && g != 0ull) {
                if (a0 == g)      keys[L] = 0ull;
                else if (a1 == g) keys[L + 64] = 0ull;
                else              keys[L + 128] = 0ull;
            }
            if (L == 0) top8[k] = g;
        }
    }
    __syncthreads();

    {
        float2 sa = ((const float2*)(sess + (size_t)row * D_DIM))[L];
        for (int cc = 0; cc < 2; ++cc) {
            int c = 2 * w + cc;
            int idx = 131071 - (int)(top8[c] & 0x1FFFFull);
            bool ok = idx < P_ROWS;
            float2 pb = ok ? ((const float2*)(pool + (size_t)idx * D_DIM))[L]
                           : make_float2(0.f, 0.f);
            double dot = (double)sa.x * pb.x + (double)sa.y * pb.y;
            double nb  = (double)pb.x * pb.x + (double)pb.y * pb.y;
            #pragma unroll
            for (int o = 32; o > 0; o >>= 1) {
                dot += __shfl_xor(dot, o);
                nb  += __shfl_xor(nb, o);
            }
            if (L == 0) {
                vv[c] = ok ? dot / sqrt(s_na * (nb + (double)D_DIM * 1e-6))
                           : -1e300;
                ii[c] = idx;
            }
        }
    }
    __syncthreads();

    if (tid == 0) {
        double v0 = -1e300, v1 = -1e300, v2 = -1e300;
        int    i0 = 0x7fffffff, i1 = 0x7fffffff, i2 = 0x7fffffff;
        for (int j = 0; j < 8; ++j) ins3d(vv[j], ii[j], v0, i0, v1, i1, v2, i2);
        double z  = (double)P_ROWS + s_dss / sqrt(s_na) + 390.625;
        double c0 = exp(v0) / z, c1 = exp(v1) / z, c2 = exp(v2) / z;
        double e1 = exp(c1 - c0), e2 = exp(c2 - c0);
        double inv = 1.0 / (1.0 + e1 + e2);
        s_w[0] = (float)inv;
        s_w[1] = (float)(e1 * inv);
        s_w[2] = (float)(e2 * inv);
        s_i[0] = i0; s_i[1] = i1; s_i[2] = i2;
    }
    __syncthreads();

    if (tid < D_DIM) {
        float g0 = pool[(size_t)s_i[0] * D_DIM + tid];
        float g1 = pool[(size_t)s_i[1] * D_DIM + tid];
        float g2 = pool[(size_t)s_i[2] * D_DIM + tid];
        out_sesstopk[((size_t)row * 3 + 0) * D_DIM + tid] = g0;
        out_sesstopk[((size_t)row * 3 + 1) * D_DIM + tid] = g1;
        out_sesstopk[((size_t)row * 3 + 2) * D_DIM + tid] = g2;
        out_neighbor[(size_t)row * D_DIM + tid] =
            s_w[0] * g0 + s_w[1] * g1 + s_w[2] * g2;
        if (tid < 3) out_costopk[row * 3 + tid] = s_w[tid];
    }
}

// ---------------------------------------------------------------------------
extern "C" void kernel_launch(void* const* d_in, const int* in_sizes, int n_in,
                              void* d_out, int out_size, void* d_ws, size_t ws_size,
                              hipStream_t stream) {
    const float* sess = (const float*)d_in[0];   // [2048,128]
    const float* pool = (const float*)d_in[1];   // [100000,128]
    float* out = (float*)d_out;
    float* out_neighbor = out;
    float* out_costopk  = out + (size_t)B_ROWS * D_DIM;
    float* out_sesstopk = out_costopk + (size_t)B_ROWS * 3;

    // ws: S(512B) | S_part(400KB) | partials(3.1MB) | sess2(512KB) | pool2(25.6MB)
    float* Svec     = (float*)d_ws;
    float* S_part   = (float*)((char*)d_ws + 512);
    u64*   partials = (u64*)((char*)d_ws + 512 + (size_t)NT * 128 * 4);
    char*  sess2    = (char*)partials + (size_t)B_ROWS * NCAND * 8;
    char*  pool2    = sess2 + (size_t)B_ROWS * 256;

    pack_kernel<<<NT + 512, 256, 0, stream>>>(sess, pool, sess2, pool2, S_part);

    dim3 g3(NPC, 17);
    gemm_topk_kernel<<<g3, 256, 0, stream>>>(sess2, pool2, partials, S_part, Svec);

    finalize_kernel<<<B_ROWS, 256, 0, stream>>>(
        sess, pool, partials, Svec, out_neighbor, out_costopk, out_sesstopk);
}